// Round 8
// baseline (203.300 us; speedup 1.0000x reference)
//
#include <hip/hip_runtime.h>

#define N_NODES 50000
#define N_EDGES 800000
#define IN_CH 256
#define HID_CH 128
#define OUT_CH 64
#define CAP 64       // bucket slots/node; deg~Poisson(16), P(deg>=64) ~ 1e-18
#define NBINS 196    // ceil(N_NODES/256): bin = dst >> 8
#define PCHUNK 3200
#define PBLOCKS 250  // ceil(N_EDGES/PCHUNK)
#define SWZ_BLOCKS ((IN_CH * HID_CH + HID_CH * OUT_CH) / 256)   // 160

typedef _Float16 f16;
typedef _Float16 f16x8 __attribute__((ext_vector_type(8)));
typedef _Float16 f16x2 __attribute__((ext_vector_type(2)));
typedef float f32x4 __attribute__((ext_vector_type(4)));
typedef unsigned short u16;
typedef unsigned int u32;

// ---------------- local exclusive scan of binCnt (per-block, in LDS) ----------------
// sc_excl[i] = sum_{j<i} binCnt[j]; also returns binCnt[i] via lcnt_out.
__device__ __forceinline__ void local_scan(const int* __restrict__ binCnt,
                                           int* sc /*[256] LDS*/,
                                           int* vout /*[256] LDS*/) {
    int t = threadIdx.x & 255;
    int v = t < NBINS ? binCnt[t] : 0;
    sc[t] = v;
    vout[t] = v;
    __syncthreads();
#pragma unroll
    for (int ofs = 1; ofs < 256; ofs <<= 1) {
        int add = (t >= ofs) ? sc[t - ofs] : 0;
        __syncthreads();
        sc[t] += add;
        __syncthreads();
    }
    // sc now inclusive; exclusive = sc[t] - vout[t]
}

// ---------------- W -> MFMA B-fragment swizzle (device body) ----------------
template <int K, int N>
__device__ __forceinline__ void swz(const float* __restrict__ W, f16* __restrict__ Bsw,
                                    int idx) {
    constexpr int NTILES = N / 16;
    int j = idx & 7;
    int lane = (idx >> 3) & 63;
    int rest = idx >> 9;
    int nt = rest % NTILES;
    int ks = rest / NTILES;
    int k = ks * 32 + (lane >> 4) * 8 + j;
    int n = nt * 16 + (lane & 15);
    Bsw[idx] = (f16)W[(size_t)k * N + n];
}

// ---------------- fused: dst-bin histogram + weight swizzle ----------------
__global__ __launch_bounds__(256) void k_pre(const int* __restrict__ dst,
                                             int* __restrict__ binCnt, int E,
                                             const float* __restrict__ W1,
                                             const float* __restrict__ W2,
                                             f16* __restrict__ B1,
                                             f16* __restrict__ B2) {
    if ((int)blockIdx.x < PBLOCKS) {
        __shared__ int lcnt[NBINS];
        for (int i = threadIdx.x; i < NBINS; i += 256) lcnt[i] = 0;
        __syncthreads();
        int base = blockIdx.x * PCHUNK;
        int end = min(base + PCHUNK, E);
        for (int i = base + (int)threadIdx.x; i < end; i += 256)
            atomicAdd(&lcnt[dst[i] >> 8], 1);
        __syncthreads();
        for (int i = threadIdx.x; i < NBINS; i += 256)
            if (lcnt[i]) atomicAdd(&binCnt[i], lcnt[i]);
        return;
    }
    int idx = ((int)blockIdx.x - PBLOCKS) * 256 + threadIdx.x;
    if (idx < IN_CH * HID_CH) {
        swz<IN_CH, HID_CH>(W1, B1, idx);
    } else {
        idx -= IN_CH * HID_CH;
        if (idx < HID_CH * OUT_CH) swz<HID_CH, OUT_CH>(W2, B2, idx);
    }
}

// ---------------- place packed (dst<<16|src) codes into bin segments ----------------
// Bin starts computed by local scan; binCursor is zero-initialized reservations.
__global__ __launch_bounds__(256) void k_place(const int* __restrict__ src,
                                               const int* __restrict__ dst,
                                               const int* __restrict__ binCnt,
                                               int* __restrict__ binCursor,
                                               u32* __restrict__ ebuf, int E) {
    __shared__ u32 codes[PCHUNK];
    __shared__ int sc[256], vv[256];
    __shared__ int lcnt[NBINS], lbase[NBINS], lcur[NBINS];
    local_scan(binCnt, sc, vv);
    for (int i = threadIdx.x; i < NBINS; i += 256) lcnt[i] = 0;
    __syncthreads();
    int base = blockIdx.x * PCHUNK;
    int m = min(PCHUNK, E - base);
    for (int j = threadIdx.x; j < m; j += 256) {
        u32 d = (u32)dst[base + j];
        codes[j] = (d << 16) | (u32)src[base + j];
        atomicAdd(&lcnt[d >> 8], 1);
    }
    __syncthreads();
    for (int i = threadIdx.x; i < NBINS; i += 256) {
        lbase[i] = (sc[i] - vv[i]) + atomicAdd(&binCursor[i], lcnt[i]);
        lcur[i] = 0;
    }
    __syncthreads();
    for (int j = threadIdx.x; j < m; j += 256) {
        u32 c = codes[j];
        int b = c >> 24;
        int p = atomicAdd(&lcur[b], 1);
        ebuf[lbase[b] + p] = c;
    }
}

// ---------------- per-bin CSR build in LDS + cnt + dis ----------------
__global__ __launch_bounds__(256) void k_build(const u32* __restrict__ ebuf,
                                               const int* __restrict__ binCnt,
                                               int* __restrict__ cnt,
                                               float* __restrict__ dis,
                                               u16* __restrict__ bucket, int N) {
    __shared__ int sc[256], vv[256];
    __shared__ int lcnt[256];
    __shared__ u16 lbuck[256 * CAP];   // 32 KB
    local_scan(binCnt, sc, vv);
    int t = threadIdx.x;
    lcnt[t] = 0;
    __syncthreads();
    int b = blockIdx.x;
    int s = sc[b] - vv[b];
    int e = sc[b];
    for (int i = s + t; i < e; i += 256) {
        u32 c = ebuf[i];
        int local = (c >> 16) & 255;
        int p = atomicAdd(&lcnt[local], 1);
        if (p < CAP) lbuck[local * CAP + p] = (u16)(c & 0xFFFFu);
    }
    __syncthreads();
    int nodeBase = b << 8;
    if (nodeBase + t < N) {
        cnt[nodeBase + t] = lcnt[t];
        dis[nodeBase + t] = rsqrtf((float)lcnt[t] + 1.0f);
    }
    const uint4* lsrc = (const uint4*)lbuck;
    uint4* gdst = (uint4*)(bucket + (size_t)nodeBase * CAP);
    for (int idx = t; idx < 256 * CAP / 8; idx += 256) {   // 16B chunks, 8/row
        int row = idx >> 3;
        if (nodeBase + row < N) gdst[idx] = lsrc[idx];
    }
}

// ---------------- MFMA fp16 GEMM: C = dis[m] * (A@B) ----------------
template <int K, int N, bool A_FP32, bool RELU>
__global__ __launch_bounds__(256) void k_gemm(const void* __restrict__ Av,
                                              const f16* __restrict__ Bsw,
                                              const float* __restrict__ dis,
                                              f16* __restrict__ C, int M) {
    constexpr int KSTEPS = K / 32, NTILES = N / 16;
    const int tid = threadIdx.x;
    const int wave = tid >> 6, lane = tid & 63;
    const int quad = lane >> 4, l16 = lane & 15;
    int row = blockIdx.x * 64 + wave * 16 + l16;
    const int rowc = row < M ? row : M - 1;

    f32x4 acc[NTILES];
#pragma unroll
    for (int t = 0; t < NTILES; ++t) acc[t] = (f32x4){0.f, 0.f, 0.f, 0.f};

#pragma unroll
    for (int ks = 0; ks < KSTEPS; ++ks) {
        f16x8 afrag;
        if (A_FP32) {
            const float* A = (const float*)Av;
            const float4* p = (const float4*)(A + (size_t)rowc * K + ks * 32 + quad * 8);
            float4 v0 = p[0], v1 = p[1];
            afrag[0] = (f16)v0.x; afrag[1] = (f16)v0.y;
            afrag[2] = (f16)v0.z; afrag[3] = (f16)v0.w;
            afrag[4] = (f16)v1.x; afrag[5] = (f16)v1.y;
            afrag[6] = (f16)v1.z; afrag[7] = (f16)v1.w;
        } else {
            const f16* A = (const f16*)Av;
            afrag = *(const f16x8*)(A + (size_t)rowc * K + ks * 32 + quad * 8);
            if (RELU) {
#pragma unroll
                for (int j = 0; j < 8; ++j)
                    afrag[j] = afrag[j] > (f16)0 ? afrag[j] : (f16)0;
            }
        }
#pragma unroll
        for (int t = 0; t < NTILES; ++t) {
            f16x8 bfrag = *(const f16x8*)(Bsw + (((size_t)ks * NTILES + t) * 64 + lane) * 8);
            acc[t] = __builtin_amdgcn_mfma_f32_16x16x32_f16(afrag, bfrag, acc[t], 0, 0, 0);
        }
    }

    int rbase = blockIdx.x * 64 + wave * 16 + quad * 4;
#pragma unroll
    for (int r = 0; r < 4; ++r) {
        int gr = rbase + r;
        if (gr < M) {
            float d = dis[gr];
#pragma unroll
            for (int t = 0; t < NTILES; ++t)
                C[(size_t)gr * N + t * 16 + l16] = (f16)(acc[t][r] * d);
        }
    }
}

// ---------------- fused pull1 + ReLU + gemm2: g2 = dis * (relu(agg1) @ W2) ----------------
// 512 threads = 8 waves; block handles 64 nodes.
// Phase A: wave w pulls 8 nodes (64 lanes = 128 ch), writes relu(agg1) rows to LDS.
// Phase B: 4 row-groups x 2 col-halves MFMA (K=128 -> 64), dis-prescale epilogue.
#define APAD 136   // 128 + 8 f16 pad: breaks 32-bank power-of-2 row stride
__global__ __launch_bounds__(512) void k_pullgemm(const f16* __restrict__ g1,
                                                  const float* __restrict__ dis,
                                                  const float* __restrict__ b1,
                                                  const int* __restrict__ cnt,
                                                  const u16* __restrict__ bucket,
                                                  const f16* __restrict__ W2sw,
                                                  f16* __restrict__ g2, int N) {
    __shared__ f16 As[64][APAD];   // 17.4 KB
    const int tid = threadIdx.x;
    const int wave = tid >> 6, lane = tid & 63;
    const int base = blockIdx.x * 64;

    // ---- Phase A: pull 8 nodes per wave ----
    float bv0 = b1[lane * 2], bv1 = b1[lane * 2 + 1];
    for (int i = 0; i < 8; ++i) {
        int uloc = wave * 8 + i;
        int u = base + uloc;
        if (u >= N) {
            f16x2 z; z[0] = (f16)0; z[1] = (f16)0;
            *(f16x2*)&As[uloc][lane * 2] = z;
            continue;
        }
        const f16* gp = g1 + lane * 2;
        f16x2 hv = *(const f16x2*)(gp + (size_t)u * HID_CH);
        float a0 = (float)hv[0], a1 = (float)hv[1];

        int n = cnt[u];
        if (n > CAP) n = CAP;
        const u16* row = bucket + u * CAP;
        int k = 0;
        for (; k + 8 <= n; k += 8) {
            uint4 iv = *(const uint4*)(row + k);
            int s0 = iv.x & 0xFFFF, s1 = iv.x >> 16;
            int s2 = iv.y & 0xFFFF, s3 = iv.y >> 16;
            int s4 = iv.z & 0xFFFF, s5 = iv.z >> 16;
            int s6 = iv.w & 0xFFFF, s7 = iv.w >> 16;
            f16x2 v0 = *(const f16x2*)(gp + (size_t)s0 * HID_CH);
            f16x2 v1 = *(const f16x2*)(gp + (size_t)s1 * HID_CH);
            f16x2 v2 = *(const f16x2*)(gp + (size_t)s2 * HID_CH);
            f16x2 v3 = *(const f16x2*)(gp + (size_t)s3 * HID_CH);
            f16x2 v4 = *(const f16x2*)(gp + (size_t)s4 * HID_CH);
            f16x2 v5 = *(const f16x2*)(gp + (size_t)s5 * HID_CH);
            f16x2 v6 = *(const f16x2*)(gp + (size_t)s6 * HID_CH);
            f16x2 v7 = *(const f16x2*)(gp + (size_t)s7 * HID_CH);
            a0 += ((float)v0[0] + (float)v1[0]) + ((float)v2[0] + (float)v3[0]) +
                  (((float)v4[0] + (float)v5[0]) + ((float)v6[0] + (float)v7[0]));
            a1 += ((float)v0[1] + (float)v1[1]) + ((float)v2[1] + (float)v3[1]) +
                  (((float)v4[1] + (float)v5[1]) + ((float)v6[1] + (float)v7[1]));
        }
        if (k + 4 <= n) {
            ushort4 s4v = *(const ushort4*)(row + k);
            f16x2 v0 = *(const f16x2*)(gp + (size_t)s4v.x * HID_CH);
            f16x2 v1 = *(const f16x2*)(gp + (size_t)s4v.y * HID_CH);
            f16x2 v2 = *(const f16x2*)(gp + (size_t)s4v.z * HID_CH);
            f16x2 v3 = *(const f16x2*)(gp + (size_t)s4v.w * HID_CH);
            a0 += ((float)v0[0] + (float)v1[0]) + ((float)v2[0] + (float)v3[0]);
            a1 += ((float)v0[1] + (float)v1[1]) + ((float)v2[1] + (float)v3[1]);
            k += 4;
        }
        for (; k < n; ++k) {
            f16x2 v = *(const f16x2*)(gp + (size_t)row[k] * HID_CH);
            a0 += (float)v[0];
            a1 += (float)v[1];
        }

        float du = dis[u];
        f16x2 o;
        o[0] = (f16)fmaxf(fmaf(du, a0, bv0), 0.f);   // relu(agg1) directly
        o[1] = (f16)fmaxf(fmaf(du, a1, bv1), 0.f);
        *(f16x2*)&As[uloc][lane * 2] = o;
    }
    __syncthreads();

    // ---- Phase B: MFMA 128 -> 64 from LDS ----
    constexpr int KSTEPS = HID_CH / 32;   // 4
    const int rg = wave >> 1;             // row-group 0..3
    const int half = wave & 1;            // col-half 0..1
    const int quad = lane >> 4, l16 = lane & 15;

    f32x4 acc[2];
    acc[0] = (f32x4){0.f, 0.f, 0.f, 0.f};
    acc[1] = (f32x4){0.f, 0.f, 0.f, 0.f};

#pragma unroll
    for (int ks = 0; ks < KSTEPS; ++ks) {
        f16x8 afrag = *(const f16x8*)&As[rg * 16 + l16][ks * 32 + quad * 8];
#pragma unroll
        for (int tt = 0; tt < 2; ++tt) {
            int nt = half * 2 + tt;
            f16x8 bfrag = *(const f16x8*)(W2sw + (((size_t)ks * 4 + nt) * 64 + lane) * 8);
            acc[tt] = __builtin_amdgcn_mfma_f32_16x16x32_f16(afrag, bfrag, acc[tt], 0, 0, 0);
        }
    }

    int rbase = base + rg * 16 + quad * 4;
#pragma unroll
    for (int r = 0; r < 4; ++r) {
        int gr = rbase + r;
        if (gr < N) {
            float d = dis[gr];
#pragma unroll
            for (int tt = 0; tt < 2; ++tt) {
                int nt = half * 2 + tt;
                g2[(size_t)gr * OUT_CH + nt * 16 + l16] = (f16)(acc[tt][r] * d);
            }
        }
    }
}

// ---------------- pull2: pure gather-sum, fused ReLU, fp32 out ----------------
__global__ __launch_bounds__(256) void k_pull2(const f16* __restrict__ g,
                                               const float* __restrict__ dis,
                                               const float* __restrict__ bias,
                                               const int* __restrict__ cnt,
                                               const u16* __restrict__ bucket,
                                               float2* __restrict__ out, int N) {
    int tid = blockIdx.x * 256 + threadIdx.x;
    int u = tid >> 5;          // 32 lanes/node, 2 ch/lane
    int sub = tid & 31;
    if (u >= N) return;
    const f16* gp = g + sub * 2;

    f16x2 hv = *(const f16x2*)(gp + (size_t)u * OUT_CH);
    float a0 = (float)hv[0], a1 = (float)hv[1];

    int n = cnt[u];
    if (n > CAP) n = CAP;
    const u16* row = bucket + u * CAP;

    int k = 0;
    for (; k + 8 <= n; k += 8) {
        uint4 iv = *(const uint4*)(row + k);
        int s0 = iv.x & 0xFFFF, s1 = iv.x >> 16;
        int s2 = iv.y & 0xFFFF, s3 = iv.y >> 16;
        int s4 = iv.z & 0xFFFF, s5 = iv.z >> 16;
        int s6 = iv.w & 0xFFFF, s7 = iv.w >> 16;
        f16x2 v0 = *(const f16x2*)(gp + (size_t)s0 * OUT_CH);
        f16x2 v1 = *(const f16x2*)(gp + (size_t)s1 * OUT_CH);
        f16x2 v2 = *(const f16x2*)(gp + (size_t)s2 * OUT_CH);
        f16x2 v3 = *(const f16x2*)(gp + (size_t)s3 * OUT_CH);
        f16x2 v4 = *(const f16x2*)(gp + (size_t)s4 * OUT_CH);
        f16x2 v5 = *(const f16x2*)(gp + (size_t)s5 * OUT_CH);
        f16x2 v6 = *(const f16x2*)(gp + (size_t)s6 * OUT_CH);
        f16x2 v7 = *(const f16x2*)(gp + (size_t)s7 * OUT_CH);
        a0 += ((float)v0[0] + (float)v1[0]) + ((float)v2[0] + (float)v3[0]) +
              (((float)v4[0] + (float)v5[0]) + ((float)v6[0] + (float)v7[0]));
        a1 += ((float)v0[1] + (float)v1[1]) + ((float)v2[1] + (float)v3[1]) +
              (((float)v4[1] + (float)v5[1]) + ((float)v6[1] + (float)v7[1]));
    }
    if (k + 4 <= n) {
        ushort4 s4v = *(const ushort4*)(row + k);
        f16x2 v0 = *(const f16x2*)(gp + (size_t)s4v.x * OUT_CH);
        f16x2 v1 = *(const f16x2*)(gp + (size_t)s4v.y * OUT_CH);
        f16x2 v2 = *(const f16x2*)(gp + (size_t)s4v.z * OUT_CH);
        f16x2 v3 = *(const f16x2*)(gp + (size_t)s4v.w * OUT_CH);
        a0 += ((float)v0[0] + (float)v1[0]) + ((float)v2[0] + (float)v3[0]);
        a1 += ((float)v0[1] + (float)v1[1]) + ((float)v2[1] + (float)v3[1]);
        k += 4;
    }
    for (; k < n; ++k) {
        f16x2 v = *(const f16x2*)(gp + (size_t)row[k] * OUT_CH);
        a0 += (float)v[0];
        a1 += (float)v[1];
    }

    float du = dis[u];
    float o0 = fmaf(du, a0, bias[sub * 2]);
    float o1 = fmaf(du, a1, bias[sub * 2 + 1]);
    out[(size_t)u * 32 + sub] = make_float2(fmaxf(o0, 0.f), fmaxf(o1, 0.f));
}

// ---------------- launch ----------------

extern "C" void kernel_launch(void* const* d_in, const int* in_sizes, int n_in,
                              void* d_out, int out_size, void* d_ws, size_t ws_size,
                              hipStream_t stream) {
    const float* x  = (const float*)d_in[0];
    const int* ei   = (const int*)d_in[1];
    const float* W1 = (const float*)d_in[2];
    const float* b1 = (const float*)d_in[3];
    const float* W2 = (const float*)d_in[4];
    const float* b2 = (const float*)d_in[5];
    float* out = (float*)d_out;

    const int* src = ei;
    const int* dst = ei + N_EDGES;

    char* ws = (char*)d_ws;
    size_t off = 0;
    auto alloc = [&](size_t bytes) -> void* {
        off = (off + 255) & ~(size_t)255;
        void* p = ws + off;
        off += bytes;
        return p;
    };
    int*   binCnt    = (int*)alloc((size_t)NBINS * 2 * 4);          // [binCnt | binCursor]
    int*   binCursor = binCnt + NBINS;
    u32*   ebuf      = (u32*)alloc((size_t)N_EDGES * 4);            // 3.2 MB
    int*   cnt       = (int*)alloc((size_t)N_NODES * 4);
    float* dis       = (float*)alloc((size_t)N_NODES * 4);
    u16*   bucket    = (u16*)alloc((size_t)N_NODES * CAP * 2);      // 6.4 MB
    f16*   W1sw      = (f16*)alloc((size_t)IN_CH * HID_CH * 2);
    f16*   W2sw      = (f16*)alloc((size_t)HID_CH * OUT_CH * 2);
    f16*   g1        = (f16*)alloc((size_t)N_NODES * HID_CH * 2);   // 12.8 MB, prescaled
    f16*   g2        = (f16*)alloc((size_t)N_NODES * OUT_CH * 2);   // 6.4 MB, prescaled

    hipMemsetAsync(binCnt, 0, (size_t)NBINS * 2 * 4, stream);

    // 1. fused histogram + weight swizzle
    k_pre<<<PBLOCKS + SWZ_BLOCKS, 256, 0, stream>>>(dst, binCnt, N_EDGES,
                                                    W1, W2, W1sw, W2sw);
    // 2. place (local scan)   3. build (local scan) + cnt + dis
    k_place<<<PBLOCKS, 256, 0, stream>>>(src, dst, binCnt, binCursor, ebuf, N_EDGES);
    k_build<<<NBINS, 256, 0, stream>>>(ebuf, binCnt, cnt, dis, bucket, N_NODES);

    // 4. layer-1 GEMM: g1 = dis*(x @ W1)
    k_gemm<IN_CH, HID_CH, true, false><<<(N_NODES + 63) / 64, 256, 0, stream>>>(
        x, W1sw, dis, g1, N_NODES);

    // 5. fused pull1 + ReLU + gemm2: g2 = dis*(relu(du*(g1[u]+sum g1[s])+b1) @ W2)
    k_pullgemm<<<(N_NODES + 63) / 64, 512, 0, stream>>>(g1, dis, b1, cnt, bucket,
                                                        W2sw, g2, N_NODES);

    // 6. pull2: out = relu(du*(g2[u]+sum g2[s]) + b2)
    k_pull2<<<(N_NODES * 32 + 255) / 256, 256, 0, stream>>>(g2, dis, b2, cnt, bucket,
                                                            (float2*)out, N_NODES);
}